// Round 23
// baseline (53.338 us; speedup 1.0000x reference)
//
#include <hip/hip_runtime.h>

#define SEQ_L 1024
#define BATCH_N 512
#define NTAG 48
#define NSEG 16
#define SEG_T 64
#define WARM 8              // Birkhoff 0.05^8 ~ 4e-11 << fp16 noise; r21-validated
#define NUMB 128            // numerator blocks: 16 step-tiles x 8 batch-chunks

typedef __fp16 h2v __attribute__((ext_vector_type(2)));
typedef __fp16 h4v __attribute__((ext_vector_type(4)));
typedef float f4v __attribute__((ext_vector_type(4)));

__device__ inline h4v pk4(float a, float b, float c, float d) {
    h2v lo = __builtin_amdgcn_cvt_pkrtz(a, b);
    h2v hi = __builtin_amdgcn_cvt_pkrtz(c, d);
    return __builtin_shufflevector(lo, hi, 0, 1, 2, 3);
}

__device__ inline float wave_sum_f(float v) {
    #pragma unroll
    for (int off = 32; off > 0; off >>= 1) v += __shfl_xor(v, off, 64);
    return v;
}
// sum across the 4 row-groups holding the same batch column (cold path only)
__device__ inline float colsum4(float part) {
    part += __shfl_xor(part, 16, 64);
    part += __shfl_xor(part, 32, 64);
    return part;
}

#define MFMA16 __builtin_amdgcn_mfma_f32_16x16x16f16

// ---- asm-pinned prefetch: 4 slots, each {3 x dwordx4 em, 1 x dword mask}.
// volatile asm keeps issue order; "=&v" outputs force live registers (no sinking).
#define QDECL(S) f4v q##S##e0, q##S##e1, q##S##e2; int q##S##mi; bool q##S##ok;

#define PFA(S, K) { \
    int i_ = base - WARM + (K); \
    int ia_ = i_ < 0 ? 0 : (i_ > 1023 ? 1023 : i_); \
    const float* p_ = em + (size_t)ia_ * (BATCH_N * NTAG) + laneoff; \
    const int* mp_ = maskp + ia_ * BATCH_N + bb + c; \
    asm volatile("global_load_dwordx4 %0, %1, off" \
                 : "=&v"(q##S##e0) : "v"(p_) : "memory"); \
    asm volatile("global_load_dwordx4 %0, %1, off offset:64" \
                 : "=&v"(q##S##e1) : "v"(p_) : "memory"); \
    asm volatile("global_load_dwordx4 %0, %1, off offset:128" \
                 : "=&v"(q##S##e2) : "v"(p_) : "memory"); \
    asm volatile("global_load_dword %0, %1, off" \
                 : "=&v"(q##S##mi) : "v"(mp_) : "memory"); \
    q##S##ok = (i_ >= 1 && i_ <= 1023); \
}

// counted wait: 16 in flight, keep 12 -> drains exactly the oldest slot's 4 loads.
// "+v" in-outs make every consumer data-depend on the wait (rule-#18 fix).
#define PWAIT(S) \
    asm volatile("s_waitcnt vmcnt(12)" \
        : "+v"(q##S##e0), "+v"(q##S##e1), "+v"(q##S##e2), "+v"(q##S##mi) \
        :: "memory");

// fwd step (verified math, rounds 9-22): C = E^T X, Cs = colsum(C) via A4,
// X' = C o F / Cs  (entries bounded by maxF -> fp16-safe).
#define STEP_FA(S, REC) { \
    f4v F0, F1, F2; \
    _Pragma("unroll") for (int j = 0; j < 4; ++j) { \
        F0[j] = __expf(q##S##e0[j]); \
        F1[j] = __expf(q##S##e1[j]); \
        F2[j] = __expf(q##S##e2[j]); \
    } \
    f4v t01_ = MFMA16(A41, Bf1, MFMA16(A40, Bf0, kz, 0, 0, 0), 0, 0, 0); \
    f4v t2_  = MFMA16(A42, Bf2, kz, 0, 0, 0); \
    f4v c01_ = MFMA16(A01, Bf1, MFMA16(A00, Bf0, kz, 0, 0, 0), 0, 0, 0); \
    f4v c2_  = MFMA16(A02, Bf2, kz, 0, 0, 0); \
    f4v d01_ = MFMA16(A11, Bf1, MFMA16(A10, Bf0, kz, 0, 0, 0), 0, 0, 0); \
    f4v d2_  = MFMA16(A12, Bf2, kz, 0, 0, 0); \
    f4v e01_ = MFMA16(A21, Bf1, MFMA16(A20, Bf0, kz, 0, 0, 0), 0, 0, 0); \
    f4v e2_  = MFMA16(A22, Bf2, kz, 0, 0, 0); \
    float s_ = t01_[0] + t2_[0]; \
    float inv_ = __builtin_amdgcn_rcpf(s_); \
    f4v C0 = c01_ + c2_; \
    f4v C1 = d01_ + d2_; \
    f4v C2 = e01_ + e2_; \
    f4v W0 = F0 * inv_, W1 = F1 * inv_, W2 = F2 * inv_; \
    f4v X0 = C0 * W0, X1 = C1 * W1, X2 = C2 * W2; \
    h4v n0_ = pk4(X0[0], X0[1], X0[2], X0[3]); \
    h4v n1_ = pk4(X1[0], X1[1], X1[2], X1[3]); \
    h4v n2_ = pk4(X2[0], X2[1], X2[2], X2[3]); \
    bool mk_ = q##S##ok && (q##S##mi != 0); \
    Bf0 = mk_ ? n0_ : Bf0; \
    Bf1 = mk_ ? n1_ : Bf1; \
    Bf2 = mk_ ? n2_ : Bf2; \
    ls += (mk_ && (REC)) ? __logf(s_) : 0.0f; \
}

// Fused kernel: blockIdx < NUMB -> numerator path (coalesced, lane = batch);
// else one wave per (batch-tile, segment): verified scan (NSEG=16).
__attribute__((amdgpu_flat_work_group_size(64,64), amdgpu_waves_per_eu(1,2)))
__global__ void crf_fused_kernel(
    const float* __restrict__ em,
    const float* __restrict__ start_t,
    const float* __restrict__ end_t,
    const float* __restrict__ trans,
    const int*   __restrict__ tags,
    const int*   __restrict__ maskp,
    float*       __restrict__ zpart,     // [NSEG][512]
    float*       __restrict__ numpart,   // [16][512]
    int*         __restrict__ cntpart) { // [16][512]
    const int lane = threadIdx.x;

    if (blockIdx.x < NUMB) {
        // ---- numerator path: tile = 64 steps, chunk = 64 batches, lane = batch
        const int tile = blockIdx.x >> 3;          // 0..15
        const int b = (blockIdx.x & 7) * 64 + lane;
        const int i0 = tile * 64;
        float np_ = 0.0f;
        int cnt = 0;
        int tagp = (tile > 0) ? tags[(size_t)(i0 - 1) * BATCH_N + b] : 0;
        #pragma unroll 4
        for (int k = 0; k < 64; ++k) {
            int i = i0 + k;
            int tg = tags[(size_t)i * BATCH_N + b];
            int m  = maskp[i * BATCH_N + b];
            cnt += (m != 0);
            if (i == 0) {
                np_ += start_t[tg] + em[(size_t)b * NTAG + tg];
            } else if (m) {
                np_ += trans[tagp * NTAG + tg] +
                       em[(size_t)i * (BATCH_N * NTAG) + (size_t)b * NTAG + tg];
            }
            tagp = tg;
        }
        numpart[tile * BATCH_N + b] = np_;
        cntpart[tile * BATCH_N + b] = cnt;
        return;
    }

    // ---- scan path (NSEG=16, SEG_T=64, WARM=8; asm-pinned 4-deep prefetch)
    const int sb  = blockIdx.x - NUMB;
    const int bt  = sb >> 4;               // batch tile 0..31
    const int seg = sb & 15;               // time segment 0..15
    const int bb = bt * 16;
    const int base = seg * SEG_T;
    const int c = lane & 15;               // batch column
    const int g = lane >> 4;               // row group (0..3)

    __shared__ float sh_w4[NTAG];
    if (lane < NTAG) {
        float s = 0.f;
        #pragma unroll 8
        for (int t2 = 0; t2 < NTAG; ++t2)
            s += __expf(trans[lane * NTAG + t2]);
        sh_w4[lane] = s;
    }
    __syncthreads();

    // constant A fragments (verified fwd mapping): A = E^T, A[m][k] = E[k][m]
    h4v A00, A01, A02, A10, A11, A12, A20, A21, A22, A40, A41, A42;
    {
        #define LOADA(MT, KT, DST) {                                           \
            float e_[4];                                                       \
            _Pragma("unroll") for (int j = 0; j < 4; ++j) {                    \
                int kidx_ = 16*(KT) + 4*g + j;                                 \
                int midx_ = 16*(MT) + c;                                       \
                e_[j] = __expf(trans[kidx_ * NTAG + midx_]);                   \
            }                                                                  \
            DST = pk4(e_[0], e_[1], e_[2], e_[3]);                             \
        }
        #define LOADA4(KT, DST) {                                              \
            float e_[4];                                                       \
            _Pragma("unroll") for (int j = 0; j < 4; ++j)                      \
                e_[j] = sh_w4[16*(KT) + 4*g + j];                              \
            DST = pk4(e_[0], e_[1], e_[2], e_[3]);                             \
        }
        LOADA(0,0,A00) LOADA(0,1,A01) LOADA(0,2,A02)
        LOADA(1,0,A10) LOADA(1,1,A11) LOADA(1,2,A12)
        LOADA(2,0,A20) LOADA(2,1,A21) LOADA(2,2,A22)
        LOADA4(0,A40)  LOADA4(1,A41)  LOADA4(2,A42)
        #undef LOADA
        #undef LOADA4
    }

    const f4v kz = {0.f, 0.f, 0.f, 0.f};
    const size_t laneoff = (size_t)(bb + c) * NTAG + (size_t)g * 4;

    h4v Bf0, Bf1, Bf2;
    float ls = 0.0f;
    if (seg == 0) {
        f4v e0 = *(const f4v*)(em + laneoff);
        f4v e1 = *(const f4v*)(em + laneoff + 16);
        f4v e2 = *(const f4v*)(em + laneoff + 32);
        float x0[4], x1[4], x2[4];
        float psum = 0.f;
        #pragma unroll
        for (int j = 0; j < 4; ++j) {
            x0[j] = __expf(start_t[ 0 + 4*g + j] + e0[j]);
            x1[j] = __expf(start_t[16 + 4*g + j] + e1[j]);
            x2[j] = __expf(start_t[32 + 4*g + j] + e2[j]);
            psum += x0[j] + x1[j] + x2[j];
        }
        float s0 = colsum4(psum);
        float inv0 = 1.0f / s0;
        ls = __logf(s0);
        Bf0 = pk4(x0[0]*inv0, x0[1]*inv0, x0[2]*inv0, x0[3]*inv0);
        Bf1 = pk4(x1[0]*inv0, x1[1]*inv0, x1[2]*inv0, x1[3]*inv0);
        Bf2 = pk4(x2[0]*inv0, x2[1]*inv0, x2[2]*inv0, x2[3]*inv0);
    } else {
        const float u = 1.0f / NTAG;
        Bf0 = pk4(u, u, u, u);
        Bf1 = pk4(u, u, u, u);
        Bf2 = pk4(u, u, u, u);
    }

    // pipeline: 4-deep asm-pinned prefetch; 8 warm-up + 64 recorded steps
    QDECL(0) QDECL(1) QDECL(2) QDECL(3)
    PFA(0,0) PFA(1,1) PFA(2,2) PFA(3,3)
    #pragma unroll 1
    for (int k = 0; k < WARM; k += 4) {              // warm-up (no record)
        PWAIT(0) STEP_FA(0,0) PFA(0, k + 4)
        PWAIT(1) STEP_FA(1,0) PFA(1, k + 5)
        PWAIT(2) STEP_FA(2,0) PFA(2, k + 6)
        PWAIT(3) STEP_FA(3,0) PFA(3, k + 7)
    }
    #pragma unroll 1
    for (int k = WARM; k < WARM + SEG_T; k += 4) {   // recorded steps
        PWAIT(0) STEP_FA(0,1) PFA(0, k + 4)
        PWAIT(1) STEP_FA(1,1) PFA(1, k + 5)
        PWAIT(2) STEP_FA(2,1) PFA(2, k + 6)
        PWAIT(3) STEP_FA(3,1) PFA(3, k + 7)
    }
    asm volatile("s_waitcnt vmcnt(0)" ::: "memory");

    if (seg == NSEG - 1) {     // end-transition term
        float d = 0.f;
        #pragma unroll
        for (int j = 0; j < 4; ++j) {
            d += __expf(end_t[ 0 + 4*g + j]) * (float)Bf0[j];
            d += __expf(end_t[16 + 4*g + j]) * (float)Bf1[j];
            d += __expf(end_t[32 + 4*g + j]) * (float)Bf2[j];
        }
        d = colsum4(d);
        ls += __logf(d);
    }

    if (lane < 16) zpart[seg * BATCH_N + bb + lane] = ls;
}

__global__ __launch_bounds__(512) void final_reduce_kernel(
    const float* __restrict__ zpart, const float* __restrict__ numpart,
    const int* __restrict__ cntpart, const int* __restrict__ tags,
    const float* __restrict__ end_t, float* __restrict__ out) {
    const int b = threadIdx.x;
    float z = 0.f;
    #pragma unroll
    for (int s = 0; s < NSEG; ++s) z += zpart[s * BATCH_N + b];
    float nm = 0.f;
    int sl = 0;
    #pragma unroll
    for (int t = 0; t < 16; ++t) {
        nm += numpart[t * BATCH_N + b];
        sl += cntpart[t * BATCH_N + b];
    }
    int last_tag = tags[(size_t)(sl - 1) * BATCH_N + b];
    nm += end_t[last_tag];
    float x = z - nm;                      // = -llh[b]
    x = wave_sum_f(x);
    __shared__ float ws[8];
    int w = threadIdx.x >> 6;
    if ((threadIdx.x & 63) == 0) ws[w] = x;
    __syncthreads();
    if (threadIdx.x == 0) {
        float t = 0.0f;
        #pragma unroll
        for (int k = 0; k < 8; ++k) t += ws[k];
        *out = t;
    }
}

extern "C" void kernel_launch(void* const* d_in, const int* in_sizes, int n_in,
                              void* d_out, int out_size, void* d_ws, size_t ws_size,
                              hipStream_t stream) {
    const float* emissions = (const float*)d_in[0];
    const float* start_t   = (const float*)d_in[1];
    const float* end_t     = (const float*)d_in[2];
    const float* trans     = (const float*)d_in[3];
    const int*   tags      = (const int*)d_in[4];
    const int*   mask      = (const int*)d_in[5];
    float* zpart  = (float*)d_ws;                      // [NSEG][512]
    float* numws  = zpart + NSEG * BATCH_N;            // [16][512]
    int*   cntws  = (int*)(numws + 16 * BATCH_N);      // [16][512]

    crf_fused_kernel<<<NUMB + 32 * NSEG, 64, 0, stream>>>(
        emissions, start_t, end_t, trans, tags, mask, zpart, numws, cntws);
    final_reduce_kernel<<<1, 512, 0, stream>>>(zpart, numws, cntws, tags,
                                               end_t, (float*)d_out);
}

// Round 24
// 40.391 us; speedup vs baseline: 1.3205x; 1.3205x over previous
//
#include <hip/hip_runtime.h>

#define SEQ_L 1024
#define BATCH_N 512
#define NTAG 48
#define NSEG 16
#define SEG_T 64
#define WARM 8              // Birkhoff 0.05^8 ~ 4e-11 << fp16 noise; r21-validated
#define NUMB 256            // numerator blocks: 32 step-tiles x 8 batch-chunks
#define NTILE 32            // num tiles (32 steps each)

typedef __fp16 h2v __attribute__((ext_vector_type(2)));
typedef __fp16 h4v __attribute__((ext_vector_type(4)));
typedef float f4v __attribute__((ext_vector_type(4)));

__device__ inline h4v pk4(float a, float b, float c, float d) {
    h2v lo = __builtin_amdgcn_cvt_pkrtz(a, b);
    h2v hi = __builtin_amdgcn_cvt_pkrtz(c, d);
    return __builtin_shufflevector(lo, hi, 0, 1, 2, 3);
}

__device__ inline float wave_sum_f(float v) {
    #pragma unroll
    for (int off = 32; off > 0; off >>= 1) v += __shfl_xor(v, off, 64);
    return v;
}
// sum across the 4 row-groups holding the same batch column (cold path only)
__device__ inline float colsum4(float part) {
    part += __shfl_xor(part, 16, 64);
    part += __shfl_xor(part, 32, 64);
    return part;
}

#define MFMA16 __builtin_amdgcn_mfma_f32_16x16x16f16

// ---- asm-pinned prefetch: 4 slots, each {3 x dwordx4 em, 1 x dword mask}.
#define QDECL(S) f4v q##S##e0, q##S##e1, q##S##e2; int q##S##mi; bool q##S##ok;

#define PFA(S, K) { \
    int i_ = base - WARM + (K); \
    int ia_ = i_ < 0 ? 0 : (i_ > 1023 ? 1023 : i_); \
    const float* p_ = em + (size_t)ia_ * (BATCH_N * NTAG) + laneoff; \
    const int* mp_ = maskp + ia_ * BATCH_N + bb + c; \
    asm volatile("global_load_dwordx4 %0, %1, off" \
                 : "=&v"(q##S##e0) : "v"(p_) : "memory"); \
    asm volatile("global_load_dwordx4 %0, %1, off offset:64" \
                 : "=&v"(q##S##e1) : "v"(p_) : "memory"); \
    asm volatile("global_load_dwordx4 %0, %1, off offset:128" \
                 : "=&v"(q##S##e2) : "v"(p_) : "memory"); \
    asm volatile("global_load_dword %0, %1, off" \
                 : "=&v"(q##S##mi) : "v"(mp_) : "memory"); \
    q##S##ok = (i_ >= 1 && i_ <= 1023); \
}

#define PWAIT(S) \
    asm volatile("s_waitcnt vmcnt(12)" \
        : "+v"(q##S##e0), "+v"(q##S##e1), "+v"(q##S##e2), "+v"(q##S##mi) \
        :: "memory");

// fwd step (verified math, rounds 9-23)
#define STEP_FA(S, REC) { \
    f4v F0, F1, F2; \
    _Pragma("unroll") for (int j = 0; j < 4; ++j) { \
        F0[j] = __expf(q##S##e0[j]); \
        F1[j] = __expf(q##S##e1[j]); \
        F2[j] = __expf(q##S##e2[j]); \
    } \
    f4v t01_ = MFMA16(A41, Bf1, MFMA16(A40, Bf0, kz, 0, 0, 0), 0, 0, 0); \
    f4v t2_  = MFMA16(A42, Bf2, kz, 0, 0, 0); \
    f4v c01_ = MFMA16(A01, Bf1, MFMA16(A00, Bf0, kz, 0, 0, 0), 0, 0, 0); \
    f4v c2_  = MFMA16(A02, Bf2, kz, 0, 0, 0); \
    f4v d01_ = MFMA16(A11, Bf1, MFMA16(A10, Bf0, kz, 0, 0, 0), 0, 0, 0); \
    f4v d2_  = MFMA16(A12, Bf2, kz, 0, 0, 0); \
    f4v e01_ = MFMA16(A21, Bf1, MFMA16(A20, Bf0, kz, 0, 0, 0), 0, 0, 0); \
    f4v e2_  = MFMA16(A22, Bf2, kz, 0, 0, 0); \
    float s_ = t01_[0] + t2_[0]; \
    float inv_ = __builtin_amdgcn_rcpf(s_); \
    f4v C0 = c01_ + c2_; \
    f4v C1 = d01_ + d2_; \
    f4v C2 = e01_ + e2_; \
    f4v W0 = F0 * inv_, W1 = F1 * inv_, W2 = F2 * inv_; \
    f4v X0 = C0 * W0, X1 = C1 * W1, X2 = C2 * W2; \
    h4v n0_ = pk4(X0[0], X0[1], X0[2], X0[3]); \
    h4v n1_ = pk4(X1[0], X1[1], X1[2], X1[3]); \
    h4v n2_ = pk4(X2[0], X2[1], X2[2], X2[3]); \
    bool mk_ = q##S##ok && (q##S##mi != 0); \
    Bf0 = mk_ ? n0_ : Bf0; \
    Bf1 = mk_ ? n1_ : Bf1; \
    Bf2 = mk_ ? n2_ : Bf2; \
    ls += (mk_ && (REC)) ? __logf(s_) : 0.0f; \
}

// Fused kernel: blockIdx < NUMB -> pipelined numerator path; else scan path.
__attribute__((amdgpu_flat_work_group_size(64,64), amdgpu_waves_per_eu(1,2)))
__global__ void crf_fused_kernel(
    const float* __restrict__ em,
    const float* __restrict__ start_t,
    const float* __restrict__ end_t,
    const float* __restrict__ trans,
    const int*   __restrict__ tags,
    const int*   __restrict__ maskp,
    float*       __restrict__ zpart,     // [NSEG][512]
    float*       __restrict__ numpart,   // [NTILE][512]
    int*         __restrict__ cntpart) { // [NTILE][512]
    const int lane = threadIdx.x;

    __shared__ float shtr[NTAG * NTAG];    // trans staged (num path); 9.2 KB
    __shared__ float sh_w4[NTAG];

    if (blockIdx.x < NUMB) {
        // ---- numerator path: tile = 32 steps, chunk = 64 batches, lane = batch.
        // Two-phase pipeline per 16-step half: {stage tags+masks} -> {16
        // independent em gathers} -> accumulate (trans from LDS).
        const int tile = blockIdx.x >> 3;          // 0..31
        const int b = (blockIdx.x & 7) * 64 + lane;
        const int i0 = tile * NTILE;
        {   // stage trans -> LDS: 576 float4, 9 per lane
            const f4v* ts_ = (const f4v*)trans;
            f4v* td_ = (f4v*)shtr;
            #pragma unroll
            for (int k = 0; k < 9; ++k) td_[k * 64 + lane] = ts_[k * 64 + lane];
        }
        __syncthreads();
        float np_ = 0.0f;
        int cnt = 0;
        int tagp = (i0 > 0) ? tags[(size_t)(i0 - 1) * BATCH_N + b] : 0;
        #pragma unroll
        for (int half = 0; half < 2; ++half) {
            const int hb = i0 + half * 16;
            int tg[16], mk[16];
            #pragma unroll
            for (int k = 0; k < 16; ++k) {
                tg[k] = tags[(size_t)(hb + k) * BATCH_N + b];
                mk[k] = maskp[(hb + k) * BATCH_N + b];
            }
            float ev[16];
            #pragma unroll
            for (int k = 0; k < 16; ++k)
                ev[k] = em[(size_t)(hb + k) * (BATCH_N * NTAG)
                           + (size_t)b * NTAG + tg[k]];
            #pragma unroll
            for (int k = 0; k < 16; ++k) {
                int i = hb + k;
                cnt += (mk[k] != 0);
                if (i == 0) {
                    np_ += start_t[tg[k]] + ev[k];
                } else if (mk[k]) {
                    np_ += shtr[tagp * NTAG + tg[k]] + ev[k];
                }
                tagp = tg[k];
            }
        }
        numpart[tile * BATCH_N + b] = np_;
        cntpart[tile * BATCH_N + b] = cnt;
        return;
    }

    // ---- scan path (NSEG=16, SEG_T=64, WARM=8; asm-pinned 4-deep prefetch)
    const int sb  = blockIdx.x - NUMB;
    const int bt  = sb >> 4;               // batch tile 0..31
    const int seg = sb & 15;               // time segment 0..15
    const int bb = bt * 16;
    const int base = seg * SEG_T;
    const int c = lane & 15;               // batch column
    const int g = lane >> 4;               // row group (0..3)

    if (lane < NTAG) {
        float s = 0.f;
        #pragma unroll 8
        for (int t2 = 0; t2 < NTAG; ++t2)
            s += __expf(trans[lane * NTAG + t2]);
        sh_w4[lane] = s;
    }
    __syncthreads();

    // constant A fragments (verified fwd mapping): A = E^T, A[m][k] = E[k][m]
    h4v A00, A01, A02, A10, A11, A12, A20, A21, A22, A40, A41, A42;
    {
        #define LOADA(MT, KT, DST) {                                           \
            float e_[4];                                                       \
            _Pragma("unroll") for (int j = 0; j < 4; ++j) {                    \
                int kidx_ = 16*(KT) + 4*g + j;                                 \
                int midx_ = 16*(MT) + c;                                       \
                e_[j] = __expf(trans[kidx_ * NTAG + midx_]);                   \
            }                                                                  \
            DST = pk4(e_[0], e_[1], e_[2], e_[3]);                             \
        }
        #define LOADA4(KT, DST) {                                              \
            float e_[4];                                                       \
            _Pragma("unroll") for (int j = 0; j < 4; ++j)                      \
                e_[j] = sh_w4[16*(KT) + 4*g + j];                              \
            DST = pk4(e_[0], e_[1], e_[2], e_[3]);                             \
        }
        LOADA(0,0,A00) LOADA(0,1,A01) LOADA(0,2,A02)
        LOADA(1,0,A10) LOADA(1,1,A11) LOADA(1,2,A12)
        LOADA(2,0,A20) LOADA(2,1,A21) LOADA(2,2,A22)
        LOADA4(0,A40)  LOADA4(1,A41)  LOADA4(2,A42)
        #undef LOADA
        #undef LOADA4
    }

    const f4v kz = {0.f, 0.f, 0.f, 0.f};
    const size_t laneoff = (size_t)(bb + c) * NTAG + (size_t)g * 4;

    h4v Bf0, Bf1, Bf2;
    float ls = 0.0f;
    if (seg == 0) {
        f4v e0 = *(const f4v*)(em + laneoff);
        f4v e1 = *(const f4v*)(em + laneoff + 16);
        f4v e2 = *(const f4v*)(em + laneoff + 32);
        float x0[4], x1[4], x2[4];
        float psum = 0.f;
        #pragma unroll
        for (int j = 0; j < 4; ++j) {
            x0[j] = __expf(start_t[ 0 + 4*g + j] + e0[j]);
            x1[j] = __expf(start_t[16 + 4*g + j] + e1[j]);
            x2[j] = __expf(start_t[32 + 4*g + j] + e2[j]);
            psum += x0[j] + x1[j] + x2[j];
        }
        float s0 = colsum4(psum);
        float inv0 = 1.0f / s0;
        ls = __logf(s0);
        Bf0 = pk4(x0[0]*inv0, x0[1]*inv0, x0[2]*inv0, x0[3]*inv0);
        Bf1 = pk4(x1[0]*inv0, x1[1]*inv0, x1[2]*inv0, x1[3]*inv0);
        Bf2 = pk4(x2[0]*inv0, x2[1]*inv0, x2[2]*inv0, x2[3]*inv0);
    } else {
        const float u = 1.0f / NTAG;
        Bf0 = pk4(u, u, u, u);
        Bf1 = pk4(u, u, u, u);
        Bf2 = pk4(u, u, u, u);
    }

    // pipeline: 4-deep asm-pinned prefetch; 8 warm-up + 64 recorded steps
    QDECL(0) QDECL(1) QDECL(2) QDECL(3)
    PFA(0,0) PFA(1,1) PFA(2,2) PFA(3,3)
    #pragma unroll 1
    for (int k = 0; k < WARM; k += 4) {              // warm-up (no record)
        PWAIT(0) STEP_FA(0,0) PFA(0, k + 4)
        PWAIT(1) STEP_FA(1,0) PFA(1, k + 5)
        PWAIT(2) STEP_FA(2,0) PFA(2, k + 6)
        PWAIT(3) STEP_FA(3,0) PFA(3, k + 7)
    }
    #pragma unroll 1
    for (int k = WARM; k < WARM + SEG_T; k += 4) {   // recorded steps
        PWAIT(0) STEP_FA(0,1) PFA(0, k + 4)
        PWAIT(1) STEP_FA(1,1) PFA(1, k + 5)
        PWAIT(2) STEP_FA(2,1) PFA(2, k + 6)
        PWAIT(3) STEP_FA(3,1) PFA(3, k + 7)
    }
    asm volatile("s_waitcnt vmcnt(0)" ::: "memory");

    if (seg == NSEG - 1) {     // end-transition term
        float d = 0.f;
        #pragma unroll
        for (int j = 0; j < 4; ++j) {
            d += __expf(end_t[ 0 + 4*g + j]) * (float)Bf0[j];
            d += __expf(end_t[16 + 4*g + j]) * (float)Bf1[j];
            d += __expf(end_t[32 + 4*g + j]) * (float)Bf2[j];
        }
        d = colsum4(d);
        ls += __logf(d);
    }

    if (lane < 16) zpart[seg * BATCH_N + bb + lane] = ls;
}

__global__ __launch_bounds__(512) void final_reduce_kernel(
    const float* __restrict__ zpart, const float* __restrict__ numpart,
    const int* __restrict__ cntpart, const int* __restrict__ tags,
    const float* __restrict__ end_t, float* __restrict__ out) {
    const int b = threadIdx.x;
    float z = 0.f;
    #pragma unroll
    for (int s = 0; s < NSEG; ++s) z += zpart[s * BATCH_N + b];
    float nm = 0.f;
    int sl = 0;
    #pragma unroll
    for (int t = 0; t < NTILE; ++t) {
        nm += numpart[t * BATCH_N + b];
        sl += cntpart[t * BATCH_N + b];
    }
    int last_tag = tags[(size_t)(sl - 1) * BATCH_N + b];
    nm += end_t[last_tag];
    float x = z - nm;                      // = -llh[b]
    x = wave_sum_f(x);
    __shared__ float ws[8];
    int w = threadIdx.x >> 6;
    if ((threadIdx.x & 63) == 0) ws[w] = x;
    __syncthreads();
    if (threadIdx.x == 0) {
        float t = 0.0f;
        #pragma unroll
        for (int k = 0; k < 8; ++k) t += ws[k];
        *out = t;
    }
}

extern "C" void kernel_launch(void* const* d_in, const int* in_sizes, int n_in,
                              void* d_out, int out_size, void* d_ws, size_t ws_size,
                              hipStream_t stream) {
    const float* emissions = (const float*)d_in[0];
    const float* start_t   = (const float*)d_in[1];
    const float* end_t     = (const float*)d_in[2];
    const float* trans     = (const float*)d_in[3];
    const int*   tags      = (const int*)d_in[4];
    const int*   mask      = (const int*)d_in[5];
    float* zpart  = (float*)d_ws;                      // [NSEG][512]
    float* numws  = zpart + NSEG * BATCH_N;            // [NTILE][512]
    int*   cntws  = (int*)(numws + NTILE * BATCH_N);   // [NTILE][512]

    crf_fused_kernel<<<NUMB + 32 * NSEG, 64, 0, stream>>>(
        emissions, start_t, end_t, trans, tags, mask, zpart, numws, cntws);
    final_reduce_kernel<<<1, 512, 0, stream>>>(zpart, numws, cntws, tags,
                                               end_t, (float*)d_out);
}

// Round 25
// 39.381 us; speedup vs baseline: 1.3544x; 1.0256x over previous
//
#include <hip/hip_runtime.h>

#define SEQ_L 1024
#define BATCH_N 512
#define NTAG 48
#define NSEG 16
#define SEG_T 64
#define WARM 4              // Birkhoff 0.05^4 ~ 6e-6 << fp16 state noise ~5e-4
#define NUMB 256            // numerator blocks: 32 step-tiles x 8 batch-chunks
#define NTILE 32            // num tiles (32 steps each)

typedef __fp16 h2v __attribute__((ext_vector_type(2)));
typedef __fp16 h4v __attribute__((ext_vector_type(4)));
typedef float f4v __attribute__((ext_vector_type(4)));

__device__ inline h4v pk4(float a, float b, float c, float d) {
    h2v lo = __builtin_amdgcn_cvt_pkrtz(a, b);
    h2v hi = __builtin_amdgcn_cvt_pkrtz(c, d);
    return __builtin_shufflevector(lo, hi, 0, 1, 2, 3);
}

__device__ inline float wave_sum_f(float v) {
    #pragma unroll
    for (int off = 32; off > 0; off >>= 1) v += __shfl_xor(v, off, 64);
    return v;
}
// sum across the 4 row-groups holding the same batch column (cold path only)
__device__ inline float colsum4(float part) {
    part += __shfl_xor(part, 16, 64);
    part += __shfl_xor(part, 32, 64);
    return part;
}

#define MFMA16 __builtin_amdgcn_mfma_f32_16x16x16f16

// ---- asm-pinned prefetch: 4 slots, each {3 x dwordx4 em, 1 x dword mask}.
#define QDECL(S) f4v q##S##e0, q##S##e1, q##S##e2; int q##S##mi; bool q##S##ok;

#define PFA(S, K) { \
    int i_ = base - WARM + (K); \
    int ia_ = i_ < 0 ? 0 : (i_ > 1023 ? 1023 : i_); \
    const float* p_ = em + (size_t)ia_ * (BATCH_N * NTAG) + laneoff; \
    const int* mp_ = maskp + ia_ * BATCH_N + bb + c; \
    asm volatile("global_load_dwordx4 %0, %1, off" \
                 : "=&v"(q##S##e0) : "v"(p_) : "memory"); \
    asm volatile("global_load_dwordx4 %0, %1, off offset:64" \
                 : "=&v"(q##S##e1) : "v"(p_) : "memory"); \
    asm volatile("global_load_dwordx4 %0, %1, off offset:128" \
                 : "=&v"(q##S##e2) : "v"(p_) : "memory"); \
    asm volatile("global_load_dword %0, %1, off" \
                 : "=&v"(q##S##mi) : "v"(mp_) : "memory"); \
    q##S##ok = (i_ >= 1 && i_ <= 1023); \
}

#define PWAIT(S) \
    asm volatile("s_waitcnt vmcnt(12)" \
        : "+v"(q##S##e0), "+v"(q##S##e1), "+v"(q##S##e2), "+v"(q##S##mi) \
        :: "memory");

// fwd step (verified math, rounds 9-24)
#define STEP_FA(S, REC) { \
    f4v F0, F1, F2; \
    _Pragma("unroll") for (int j = 0; j < 4; ++j) { \
        F0[j] = __expf(q##S##e0[j]); \
        F1[j] = __expf(q##S##e1[j]); \
        F2[j] = __expf(q##S##e2[j]); \
    } \
    f4v t01_ = MFMA16(A41, Bf1, MFMA16(A40, Bf0, kz, 0, 0, 0), 0, 0, 0); \
    f4v t2_  = MFMA16(A42, Bf2, kz, 0, 0, 0); \
    f4v c01_ = MFMA16(A01, Bf1, MFMA16(A00, Bf0, kz, 0, 0, 0), 0, 0, 0); \
    f4v c2_  = MFMA16(A02, Bf2, kz, 0, 0, 0); \
    f4v d01_ = MFMA16(A11, Bf1, MFMA16(A10, Bf0, kz, 0, 0, 0), 0, 0, 0); \
    f4v d2_  = MFMA16(A12, Bf2, kz, 0, 0, 0); \
    f4v e01_ = MFMA16(A21, Bf1, MFMA16(A20, Bf0, kz, 0, 0, 0), 0, 0, 0); \
    f4v e2_  = MFMA16(A22, Bf2, kz, 0, 0, 0); \
    float s_ = t01_[0] + t2_[0]; \
    float inv_ = __builtin_amdgcn_rcpf(s_); \
    f4v C0 = c01_ + c2_; \
    f4v C1 = d01_ + d2_; \
    f4v C2 = e01_ + e2_; \
    f4v W0 = F0 * inv_, W1 = F1 * inv_, W2 = F2 * inv_; \
    f4v X0 = C0 * W0, X1 = C1 * W1, X2 = C2 * W2; \
    h4v n0_ = pk4(X0[0], X0[1], X0[2], X0[3]); \
    h4v n1_ = pk4(X1[0], X1[1], X1[2], X1[3]); \
    h4v n2_ = pk4(X2[0], X2[1], X2[2], X2[3]); \
    bool mk_ = q##S##ok && (q##S##mi != 0); \
    Bf0 = mk_ ? n0_ : Bf0; \
    Bf1 = mk_ ? n1_ : Bf1; \
    Bf2 = mk_ ? n2_ : Bf2; \
    ls += (mk_ && (REC)) ? __logf(s_) : 0.0f; \
}

// Fused kernel: blockIdx < NUMB -> pipelined numerator path; else scan path.
__attribute__((amdgpu_flat_work_group_size(64,64), amdgpu_waves_per_eu(1,2)))
__global__ void crf_fused_kernel(
    const float* __restrict__ em,
    const float* __restrict__ start_t,
    const float* __restrict__ end_t,
    const float* __restrict__ trans,
    const int*   __restrict__ tags,
    const int*   __restrict__ maskp,
    float*       __restrict__ zpart,     // [NSEG][512]
    float*       __restrict__ numpart,   // [NTILE][512]
    int*         __restrict__ cntpart) { // [NTILE][512]
    const int lane = threadIdx.x;

    __shared__ float shtr[NTAG * NTAG];    // trans staged (num path); 9.2 KB
    __shared__ float sh_w4[NTAG];

    if (blockIdx.x < NUMB) {
        // ---- numerator path: tile = 32 steps, chunk = 64 batches, lane = batch.
        // Two-phase pipeline per 16-step half: {stage tags+masks} -> {16
        // independent em gathers} -> accumulate (trans from LDS).
        const int tile = blockIdx.x >> 3;          // 0..31
        const int b = (blockIdx.x & 7) * 64 + lane;
        const int i0 = tile * NTILE;
        {   // stage trans -> LDS: 576 float4, 9 per lane
            const f4v* ts_ = (const f4v*)trans;
            f4v* td_ = (f4v*)shtr;
            #pragma unroll
            for (int k = 0; k < 9; ++k) td_[k * 64 + lane] = ts_[k * 64 + lane];
        }
        __syncthreads();
        float np_ = 0.0f;
        int cnt = 0;
        int tagp = (i0 > 0) ? tags[(size_t)(i0 - 1) * BATCH_N + b] : 0;
        #pragma unroll
        for (int half = 0; half < 2; ++half) {
            const int hb = i0 + half * 16;
            int tg[16], mk[16];
            #pragma unroll
            for (int k = 0; k < 16; ++k) {
                tg[k] = tags[(size_t)(hb + k) * BATCH_N + b];
                mk[k] = maskp[(hb + k) * BATCH_N + b];
            }
            float ev[16];
            #pragma unroll
            for (int k = 0; k < 16; ++k)
                ev[k] = em[(size_t)(hb + k) * (BATCH_N * NTAG)
                           + (size_t)b * NTAG + tg[k]];
            #pragma unroll
            for (int k = 0; k < 16; ++k) {
                int i = hb + k;
                cnt += (mk[k] != 0);
                if (i == 0) {
                    np_ += start_t[tg[k]] + ev[k];
                } else if (mk[k]) {
                    np_ += shtr[tagp * NTAG + tg[k]] + ev[k];
                }
                tagp = tg[k];
            }
        }
        numpart[tile * BATCH_N + b] = np_;
        cntpart[tile * BATCH_N + b] = cnt;
        return;
    }

    // ---- scan path (NSEG=16, SEG_T=64, WARM=4; asm-pinned 4-deep prefetch)
    const int sb  = blockIdx.x - NUMB;
    const int bt  = sb >> 4;               // batch tile 0..31
    const int seg = sb & 15;               // time segment 0..15
    const int bb = bt * 16;
    const int base = seg * SEG_T;
    const int c = lane & 15;               // batch column
    const int g = lane >> 4;               // row group (0..3)

    if (lane < NTAG) {
        float s = 0.f;
        #pragma unroll 8
        for (int t2 = 0; t2 < NTAG; ++t2)
            s += __expf(trans[lane * NTAG + t2]);
        sh_w4[lane] = s;
    }
    __syncthreads();

    // constant A fragments (verified fwd mapping): A = E^T, A[m][k] = E[k][m]
    h4v A00, A01, A02, A10, A11, A12, A20, A21, A22, A40, A41, A42;
    {
        #define LOADA(MT, KT, DST) {                                           \
            float e_[4];                                                       \
            _Pragma("unroll") for (int j = 0; j < 4; ++j) {                    \
                int kidx_ = 16*(KT) + 4*g + j;                                 \
                int midx_ = 16*(MT) + c;                                       \
                e_[j] = __expf(trans[kidx_ * NTAG + midx_]);                   \
            }                                                                  \
            DST = pk4(e_[0], e_[1], e_[2], e_[3]);                             \
        }
        #define LOADA4(KT, DST) {                                              \
            float e_[4];                                                       \
            _Pragma("unroll") for (int j = 0; j < 4; ++j)                      \
                e_[j] = sh_w4[16*(KT) + 4*g + j];                              \
            DST = pk4(e_[0], e_[1], e_[2], e_[3]);                             \
        }
        LOADA(0,0,A00) LOADA(0,1,A01) LOADA(0,2,A02)
        LOADA(1,0,A10) LOADA(1,1,A11) LOADA(1,2,A12)
        LOADA(2,0,A20) LOADA(2,1,A21) LOADA(2,2,A22)
        LOADA4(0,A40)  LOADA4(1,A41)  LOADA4(2,A42)
        #undef LOADA
        #undef LOADA4
    }

    const f4v kz = {0.f, 0.f, 0.f, 0.f};
    const size_t laneoff = (size_t)(bb + c) * NTAG + (size_t)g * 4;

    h4v Bf0, Bf1, Bf2;
    float ls = 0.0f;
    if (seg == 0) {
        f4v e0 = *(const f4v*)(em + laneoff);
        f4v e1 = *(const f4v*)(em + laneoff + 16);
        f4v e2 = *(const f4v*)(em + laneoff + 32);
        float x0[4], x1[4], x2[4];
        float psum = 0.f;
        #pragma unroll
        for (int j = 0; j < 4; ++j) {
            x0[j] = __expf(start_t[ 0 + 4*g + j] + e0[j]);
            x1[j] = __expf(start_t[16 + 4*g + j] + e1[j]);
            x2[j] = __expf(start_t[32 + 4*g + j] + e2[j]);
            psum += x0[j] + x1[j] + x2[j];
        }
        float s0 = colsum4(psum);
        float inv0 = 1.0f / s0;
        ls = __logf(s0);
        Bf0 = pk4(x0[0]*inv0, x0[1]*inv0, x0[2]*inv0, x0[3]*inv0);
        Bf1 = pk4(x1[0]*inv0, x1[1]*inv0, x1[2]*inv0, x1[3]*inv0);
        Bf2 = pk4(x2[0]*inv0, x2[1]*inv0, x2[2]*inv0, x2[3]*inv0);
    } else {
        const float u = 1.0f / NTAG;
        Bf0 = pk4(u, u, u, u);
        Bf1 = pk4(u, u, u, u);
        Bf2 = pk4(u, u, u, u);
    }

    // pipeline: 4-deep asm-pinned prefetch; 4 warm-up + 64 recorded steps
    QDECL(0) QDECL(1) QDECL(2) QDECL(3)
    PFA(0,0) PFA(1,1) PFA(2,2) PFA(3,3)
    #pragma unroll 1
    for (int k = 0; k < WARM; k += 4) {              // warm-up (no record)
        PWAIT(0) STEP_FA(0,0) PFA(0, k + 4)
        PWAIT(1) STEP_FA(1,0) PFA(1, k + 5)
        PWAIT(2) STEP_FA(2,0) PFA(2, k + 6)
        PWAIT(3) STEP_FA(3,0) PFA(3, k + 7)
    }
    #pragma unroll 1
    for (int k = WARM; k < WARM + SEG_T; k += 4) {   // recorded steps
        PWAIT(0) STEP_FA(0,1) PFA(0, k + 4)
        PWAIT(1) STEP_FA(1,1) PFA(1, k + 5)
        PWAIT(2) STEP_FA(2,1) PFA(2, k + 6)
        PWAIT(3) STEP_FA(3,1) PFA(3, k + 7)
    }
    asm volatile("s_waitcnt vmcnt(0)" ::: "memory");

    if (seg == NSEG - 1) {     // end-transition term
        float d = 0.f;
        #pragma unroll
        for (int j = 0; j < 4; ++j) {
            d += __expf(end_t[ 0 + 4*g + j]) * (float)Bf0[j];
            d += __expf(end_t[16 + 4*g + j]) * (float)Bf1[j];
            d += __expf(end_t[32 + 4*g + j]) * (float)Bf2[j];
        }
        d = colsum4(d);
        ls += __logf(d);
    }

    if (lane < 16) zpart[seg * BATCH_N + bb + lane] = ls;
}

__global__ __launch_bounds__(512) void final_reduce_kernel(
    const float* __restrict__ zpart, const float* __restrict__ numpart,
    const int* __restrict__ cntpart, const int* __restrict__ tags,
    const float* __restrict__ end_t, float* __restrict__ out) {
    const int b = threadIdx.x;
    float z = 0.f;
    #pragma unroll
    for (int s = 0; s < NSEG; ++s) z += zpart[s * BATCH_N + b];
    float nm = 0.f;
    int sl = 0;
    #pragma unroll
    for (int t = 0; t < NTILE; ++t) {
        nm += numpart[t * BATCH_N + b];
        sl += cntpart[t * BATCH_N + b];
    }
    int last_tag = tags[(size_t)(sl - 1) * BATCH_N + b];
    nm += end_t[last_tag];
    float x = z - nm;                      // = -llh[b]
    x = wave_sum_f(x);
    __shared__ float ws[8];
    int w = threadIdx.x >> 6;
    if ((threadIdx.x & 63) == 0) ws[w] = x;
    __syncthreads();
    if (threadIdx.x == 0) {
        float t = 0.0f;
        #pragma unroll
        for (int k = 0; k < 8; ++k) t += ws[k];
        *out = t;
    }
}

extern "C" void kernel_launch(void* const* d_in, const int* in_sizes, int n_in,
                              void* d_out, int out_size, void* d_ws, size_t ws_size,
                              hipStream_t stream) {
    const float* emissions = (const float*)d_in[0];
    const float* start_t   = (const float*)d_in[1];
    const float* end_t     = (const float*)d_in[2];
    const float* trans     = (const float*)d_in[3];
    const int*   tags      = (const int*)d_in[4];
    const int*   mask      = (const int*)d_in[5];
    float* zpart  = (float*)d_ws;                      // [NSEG][512]
    float* numws  = zpart + NSEG * BATCH_N;            // [NTILE][512]
    int*   cntws  = (int*)(numws + NTILE * BATCH_N);   // [NTILE][512]

    crf_fused_kernel<<<NUMB + 32 * NSEG, 64, 0, stream>>>(
        emissions, start_t, end_t, trans, tags, mask, zpart, numws, cntws);
    final_reduce_kernel<<<1, 512, 0, stream>>>(zpart, numws, cntws, tags,
                                               end_t, (float*)d_out);
}